// Round 3
// baseline (408.601 us; speedup 1.0000x reference)
//
#include <hip/hip_runtime.h>
#include <hip/hip_fp16.h>

// ---------------------------------------------------------------------------
// RelGraphConv (basis-decomposed, right-norm, sum over relations) on MI355X.
//
//   h[d] = B0^T * A0[d] + B1^T * A1[d] + x[d]@Wl + bias,  ReLU
//   A_b[d] = sum_{edges e->d} (coeff[r_e][b]/deg[r_e][d]) * x[src_e]
// R14: fused gather+GEMM, 32-row tiles.
// R15: scans re-tiled 1024->256/block. launch_bounds(256,8) NEUTRAL ->
//   gather is latency-bound per-wave, not wave-starved.
// R16: quarter-wave 16-edge predicated gather: 115->100us. VALU 43%,
//   HBM 26%, MFMA 4% -> mixed latency regime: per-round dep chain
//   (recs->xb ~1000cyc) + per-node serialization + block imbalance.
// R17: EDGE-CENTRIC streaming gather. recs is CSR(dst)-sorted, so a block's
//   edges are contiguous. dloc (dst&31) packed in rec.x high bits. Each
//   16-lane group streams a contiguous edge chunk, register-accumulating
//   while dloc unchanged (avg run ~12), flushing 16 ds_add_f32 on change
//   (~3 flushes/lane/block). Per-lane independent iterations (next rec
//   preloaded, xb load issued before flush branch) -> deep MLP, no
//   shuffles, no per-node rounds, no imbalance. agg is f32[32][260]
//   (33.3KB, 4 blocks/CU); GEMM A-frags cvt f32->bf16 on read (same f2bf
//   rounding as before -> identical numerics).
// ---------------------------------------------------------------------------

#define DFEAT 128
#define NREL 8
#define AF_LDA 260   // f32 agg row stride (256 data + 4 pad -> 4-bank skew)

typedef __attribute__((ext_vector_type(8))) short bf16x8;
typedef __attribute__((ext_vector_type(4))) float f32x4;
typedef __attribute__((ext_vector_type(2))) float f32x2;

__device__ __forceinline__ ushort f2bf(float f) {
    unsigned u = __float_as_uint(f);
    u += 0x7FFF + ((u >> 16) & 1);          // round-to-nearest-even
    return (ushort)(u >> 16);
}
__device__ __forceinline__ float bflo(unsigned u) { return __uint_as_float(u << 16); }
__device__ __forceinline__ float bfhi(unsigned u) { return __uint_as_float(u & 0xFFFF0000u); }

// Fused: count_rank (atomic-latency-bound) + convert_x + build_w2T (BW-bound).
// deg must be pre-zeroed. w2T[j][k]: k<256 -> bases[k>>7][k&127][j],
// else loopw[k-256][j].
__global__ void fused_pre(const int* __restrict__ dst, int* __restrict__ deg,
                          ushort* __restrict__ rank,
                          const float* __restrict__ x, ushort* __restrict__ xb,
                          const float* __restrict__ bases, const float* __restrict__ loopw,
                          ushort* __restrict__ w2T,
                          int RE, int E, int N, int n4) {
    const int stride = gridDim.x * blockDim.x;
    const int t0 = blockIdx.x * blockDim.x + threadIdx.x;
    for (int i = t0; i < RE; i += stride) {
        int r = i / E;
        int d = dst[i];
        rank[i] = (ushort)atomicAdd(&deg[r * N + d], 1);
    }
    for (int i = t0; i < n4; i += stride) {
        float4 v = ((const float4*)x)[i];
        ushort4 o;
        o.x = f2bf(v.x); o.y = f2bf(v.y); o.z = f2bf(v.z); o.w = f2bf(v.w);
        ((ushort4*)xb)[i] = o;
    }
    for (int i = t0; i < 128 * 384; i += stride) {
        int j = i / 384, k = i % 384;
        float v = (k < 256) ? bases[(k >> 7) * DFEAT * DFEAT + (k & 127) * DFEAT + j]
                            : loopw[(k - 256) * DFEAT + j];
        w2T[i] = f2bf(v);
    }
}

// Per 256-node chunk: cnt[d] = sum_r deg[r][d]; bsums[b] = chunk total.
__global__ void scan_block_sums(const int* __restrict__ deg, int* __restrict__ cnt,
                                int* __restrict__ bsums, int N) {
    __shared__ int sdata[256];
    int b = blockIdx.x, t = threadIdx.x;
    int idx = b * 256 + t;
    int sum = 0;
    if (idx < N) {
        #pragma unroll
        for (int r = 0; r < NREL; ++r) sum += deg[r * N + idx];
        cnt[idx] = sum;
    }
    sdata[t] = sum; __syncthreads();
    for (int s = 128; s > 0; s >>= 1) {
        if (t < s) sdata[t] += sdata[t + s];
        __syncthreads();
    }
    if (t == 0) bsums[b] = sdata[0];
}

// single-block exclusive scan of bsums[nb], nb <= 1024
__global__ void scan_mid(int* __restrict__ bsums, int nb) {
    __shared__ int s[256];
    int t = threadIdx.x;
    int base = t * 4;
    int v[4]; int sum = 0;
    #pragma unroll
    for (int i = 0; i < 4; ++i) {
        v[i] = sum;
        int c = (base + i < nb) ? bsums[base + i] : 0;
        sum += c;
    }
    s[t] = sum; __syncthreads();
    for (int off = 1; off < 256; off <<= 1) {
        int add = (t >= off) ? s[t - off] : 0;
        __syncthreads();
        s[t] += add;
        __syncthreads();
    }
    int excl = (t == 0) ? 0 : s[t - 1];
    #pragma unroll
    for (int i = 0; i < 4; ++i)
        if (base + i < nb) bsums[base + i] = excl + v[i];
}

// rowStart[d] + packed[r*N+d] = ((rowStart[d]+prefix_r)<<11)|deg_rd
__global__ void scan_write(const int* __restrict__ cnt, const int* __restrict__ bsums,
                           const int* __restrict__ deg,
                           int* __restrict__ rowStart, unsigned* __restrict__ packed,
                           int N) {
    __shared__ int tsum[256];
    int b = blockIdx.x, t = threadIdx.x;
    int idx = b * 256 + t;
    int c = (idx < N) ? cnt[idx] : 0;
    tsum[t] = c; __syncthreads();
    for (int off = 1; off < 256; off <<= 1) {
        int x = 0;
        if (t >= off) x = tsum[t - off];
        __syncthreads();
        if (t >= off) tsum[t] += x;
        __syncthreads();
    }
    int excl = (t == 0) ? 0 : tsum[t - 1];   // exclusive within block
    if (idx < N) {
        int rs = bsums[b] + excl;
        rowStart[idx] = rs;
        int pre = 0;
        #pragma unroll
        for (int r = 0; r < NREL; ++r) {
            int dv = deg[r * N + idx];
            packed[r * N + idx] = ((unsigned)(rs + pre) << 11) | (unsigned)dv;
            pre += dv;
        }
    }
}

// Atomic-free placement: pos = (packed>>11) + rank. ONE random read per edge.
// R17: rec.x = src | (dst&31)<<27  (src<2^17, dloc 5 bits; blocks 32-aligned)
__global__ void fill_kernel(const int* __restrict__ src, const int* __restrict__ dst,
                            const float* __restrict__ coeff,
                            const ushort* __restrict__ rank,
                            const unsigned* __restrict__ packed,
                            uint2* __restrict__ recs, int RE, int E, int N) {
    int idx = blockIdx.x * blockDim.x + threadIdx.x;
    if (idx >= RE) return;
    int r = idx / E;
    int d = dst[idx];
    unsigned p = packed[r * N + d];
    int pos = (int)(p >> 11) + (int)rank[idx];
    float inv = 1.0f / (float)(p & 2047u);
    __half2 hc = __floats2half2_rn(coeff[2 * r] * inv, coeff[2 * r + 1] * inv);
    uint2 rec;
    rec.x = (unsigned)src[idx] | ((unsigned)(d & 31) << 27);
    rec.y = *(unsigned*)&hc;
    recs[pos] = rec;
}

// ---------------------------------------------------------------------------
// FUSED gather + GEMM. Block = 32 dst nodes, LDS agg f32[32][260] = 33.3KB.
// Phase 1 (R17): block's edges are contiguous [rowStart[row0],
//   rowStart[row0+32]). 16 groups of 16 lanes each stream a contiguous
//   chunk; lane owns 8 feats; register-accumulate per dst run, ds_add_f32
//   flush on dloc change. __syncthreads after zero-init and after stream.
// Phase 2: out[32,128] = relu([agg|xb][32,384] @ w2T^T + bias); A-frags
//   kt 0,1 read f32 agg + f2bf cvt; kt 2 from xb.
// ---------------------------------------------------------------------------
__global__ __launch_bounds__(256, 4) void gather_gemm(
    const uint2* __restrict__ recs, const int* __restrict__ rowStart,
    const ushort* __restrict__ xb,
    const ushort* __restrict__ w2T, const float* __restrict__ bias,
    float* __restrict__ out, int N, int RE) {
    __shared__ __align__(16) float aggf[32 * AF_LDA];   // 33.3 KB
    const int tid = threadIdx.x;
    const int wave = tid >> 6, lane = tid & 63;
    const int row0 = blockIdx.x * 32;

    // ---- zero agg ----
    {
        uint4 z = {0u, 0u, 0u, 0u};
        #pragma unroll
        for (int i = 0; i < 9; ++i) {
            int idx = tid + i * 256;
            if (idx < (32 * AF_LDA) / 4)
                ((uint4*)aggf)[idx] = z;
        }
    }
    __syncthreads();

    // ---- phase 1: stream edges ----
    {
        const int qb = tid >> 4;        // group 0..15
        const int h  = tid & 15;        // feature slot: feats 8h..8h+7
        const int e0 = rowStart[row0];
        const int e1 = (row0 + 32 < N) ? rowStart[row0 + 32] : RE;
        const int cntE = e1 - e0;
        const int per = (cntE + 15) >> 4;
        int qa = qb * per;      if (qa > cntE) qa = cntE;
        int qe = qa + per;      if (qe > cntE) qe = cntE;
        qa += e0; qe += e0;

        f32x2 A0 = {0.f,0.f}, A1 = {0.f,0.f}, A2 = {0.f,0.f}, A3 = {0.f,0.f};
        f32x2 B0 = {0.f,0.f}, B1 = {0.f,0.f}, B2 = {0.f,0.f}, B3 = {0.f,0.f};
        int cur = -1;

        #define FLUSH(C) { float* p = aggf + (C) * AF_LDA + h * 8;      \
            atomicAdd(p + 0, A0.x);   atomicAdd(p + 1, A0.y);           \
            atomicAdd(p + 2, A1.x);   atomicAdd(p + 3, A1.y);           \
            atomicAdd(p + 4, A2.x);   atomicAdd(p + 5, A2.y);           \
            atomicAdd(p + 6, A3.x);   atomicAdd(p + 7, A3.y);           \
            atomicAdd(p + 128, B0.x); atomicAdd(p + 129, B0.y);         \
            atomicAdd(p + 130, B1.x); atomicAdd(p + 131, B1.y);         \
            atomicAdd(p + 132, B2.x); atomicAdd(p + 133, B2.y);         \
            atomicAdd(p + 134, B3.x); atomicAdd(p + 135, B3.y); }

        if (qa < qe) {
            uint2 rec = recs[qa];
            for (int e = qa; e < qe; ++e) {
                uint2 nrec = rec;
                if (e + 1 < qe) nrec = recs[e + 1];          // prefetch next
                unsigned srcI = rec.x & 0x07FFFFFFu;
                int dloc = (int)(rec.x >> 27);
                uint4 uu = *(const uint4*)(xb + (size_t)srcI * DFEAT + h * 8);
                if (dloc != cur) {                           // rare (~run len 12)
                    if (cur >= 0) FLUSH(cur)
                    A0 = {0.f,0.f}; A1 = {0.f,0.f}; A2 = {0.f,0.f}; A3 = {0.f,0.f};
                    B0 = {0.f,0.f}; B1 = {0.f,0.f}; B2 = {0.f,0.f}; B3 = {0.f,0.f};
                    cur = dloc;
                }
                __half2 hc = *(__half2*)&rec.y;
                float c0 = __low2float(hc), c1 = __high2float(hc);
                f32x2 cc0 = {c0, c0}, cc1 = {c1, c1};
                f32x2 f01 = {bflo(uu.x), bfhi(uu.x)};
                f32x2 f23 = {bflo(uu.y), bfhi(uu.y)};
                f32x2 f45 = {bflo(uu.z), bfhi(uu.z)};
                f32x2 f67 = {bflo(uu.w), bfhi(uu.w)};
                A0 += cc0 * f01; A1 += cc0 * f23; A2 += cc0 * f45; A3 += cc0 * f67;
                B0 += cc1 * f01; B1 += cc1 * f23; B2 += cc1 * f45; B3 += cc1 * f67;
                rec = nrec;
            }
            FLUSH(cur)
        }
        #undef FLUSH
    }
    __syncthreads();

    // ---- phase 2: GEMM (M=32) ----
    const int quad = lane >> 4, l16 = lane & 15;
    int arow[2];
    #pragma unroll
    for (int m = 0; m < 2; ++m) {
        int r = row0 + m * 16 + l16;
        arow[m] = (r < N) ? r : 0;
    }

    f32x4 zero = {0.f, 0.f, 0.f, 0.f};
    f32x4 acc[2][2] = {{zero, zero}, {zero, zero}};

    #pragma unroll
    for (int kt = 0; kt < 3; ++kt) {
        bf16x8 bq[4][2];
        #pragma unroll
        for (int t = 0; t < 4; ++t)
            #pragma unroll
            for (int g = 0; g < 2; ++g)
                bq[t][g] = *(const bf16x8*)(w2T + (size_t)(wave * 32 + g * 16 + l16) * 384
                                            + kt * 128 + t * 32 + quad * 8);
        #pragma unroll
        for (int m = 0; m < 2; ++m) {
            #pragma unroll
            for (int t = 0; t < 4; ++t) {
                bf16x8 a;
                if (kt < 2) {
                    const float* ap = aggf + (size_t)(m * 16 + l16) * AF_LDA
                                      + kt * 128 + t * 32 + quad * 8;
                    f32x4 lo = *(const f32x4*)ap;
                    f32x4 hi = *(const f32x4*)(ap + 4);
                    union { bf16x8 v; ushort s[8]; } ua;
                    ua.s[0] = f2bf(lo.x); ua.s[1] = f2bf(lo.y);
                    ua.s[2] = f2bf(lo.z); ua.s[3] = f2bf(lo.w);
                    ua.s[4] = f2bf(hi.x); ua.s[5] = f2bf(hi.y);
                    ua.s[6] = f2bf(hi.z); ua.s[7] = f2bf(hi.w);
                    a = ua.v;
                } else {
                    a = *(const bf16x8*)(xb + (size_t)arow[m] * DFEAT + t * 32 + quad * 8);
                }
                acc[m][0] = __builtin_amdgcn_mfma_f32_16x16x32_bf16(a, bq[t][0], acc[m][0], 0, 0, 0);
                acc[m][1] = __builtin_amdgcn_mfma_f32_16x16x32_bf16(a, bq[t][1], acc[m][1], 0, 0, 0);
            }
        }
    }

    #pragma unroll
    for (int g = 0; g < 2; ++g) {
        int c = wave * 32 + g * 16 + l16;
        float bv = bias[c];
        #pragma unroll
        for (int m = 0; m < 2; ++m) {
            #pragma unroll
            for (int reg = 0; reg < 4; ++reg) {
                int grow = row0 + m * 16 + quad * 4 + reg;
                if (grow < N)
                    out[(size_t)grow * DFEAT + c] = fmaxf(acc[m][g][reg] + bv, 0.f);
            }
        }
    }
}

extern "C" void kernel_launch(void* const* d_in, const int* in_sizes, int n_in,
                              void* d_out, int out_size, void* d_ws, size_t ws_size,
                              hipStream_t stream) {
    const float* x     = (const float*)d_in[0];
    const int*   src   = (const int*)  d_in[1];
    const int*   dst   = (const int*)  d_in[2];
    const float* coeff = (const float*)d_in[3];
    const float* bases = (const float*)d_in[4];
    const float* loopw = (const float*)d_in[5];
    const float* bias  = (const float*)d_in[6];
    float* out = (float*)d_out;

    const int N  = in_sizes[0] / DFEAT;            // 100000
    const int RE = in_sizes[1];                    // R*E = 1200000
    const int B  = in_sizes[4] / (DFEAT * DFEAT);  // 2
    const int R  = in_sizes[3] / B;                // 8
    const int E  = RE / R;                         // 150000
    const int NB = (N + 255) / 256;                // scan blocks (391)

    // workspace layout
    char* ws = (char*)d_ws;
    size_t off = 0;
    auto alloc = [&](size_t bytes) { void* p = ws + off; off = (off + bytes + 255) & ~(size_t)255; return p; };
    int*      deg      = (int*)     alloc((size_t)R * N * sizeof(int));     // 3.2 MB
    ushort*   rank     = (ushort*)  alloc((size_t)RE * sizeof(ushort));     // 2.4 MB
    unsigned* packed   = (unsigned*)alloc((size_t)R * N * sizeof(unsigned));// 3.2 MB
    int*      cnt      = (int*)     alloc((size_t)N * sizeof(int));
    int*      rowStart = (int*)     alloc((size_t)N * sizeof(int));
    int*      bsums    = (int*)     alloc((size_t)NB * sizeof(int));
    ushort*   w2T      = (ushort*)  alloc((size_t)128 * 384 * sizeof(ushort));
    ushort*   xb       = (ushort*)  alloc((size_t)N * DFEAT * sizeof(ushort)); // 25.6 MB
    uint2*    recs     = (uint2*)   alloc((size_t)RE * sizeof(uint2));         // 9.6 MB

    hipMemsetAsync(deg, 0, (size_t)R * N * sizeof(int), stream);
    fused_pre<<<4096, 256, 0, stream>>>(dst, deg, rank, x, xb, bases, loopw, w2T,
                                        RE, E, N, N * 32);
    scan_block_sums<<<NB, 256, 0, stream>>>(deg, cnt, bsums, N);
    scan_mid<<<1, 256, 0, stream>>>(bsums, NB);
    scan_write<<<NB, 256, 0, stream>>>(cnt, bsums, deg, rowStart, packed, N);
    fill_kernel<<<(RE + 255) / 256, 256, 0, stream>>>(src, dst, coeff, rank, packed,
                                                      recs, RE, E, N);

    gather_gemm<<<(N + 31) / 32, 256, 0, stream>>>(recs, rowStart, xb, w2T,
                                                   bias, out, N, RE);
}

// Round 4
// 301.114 us; speedup vs baseline: 1.3570x; 1.3570x over previous
//
#include <hip/hip_runtime.h>
#include <hip/hip_fp16.h>

// ---------------------------------------------------------------------------
// RelGraphConv (basis-decomposed, right-norm, sum over relations) on MI355X.
//
//   h[d] = B0^T * A0[d] + B1^T * A1[d] + x[d]@Wl + bias,  ReLU
//   A_b[d] = sum_{edges e->d} (coeff[r_e][b]/deg[r_e][d]) * x[src_e]
// R14: fused gather+GEMM, 32-row tiles.
// R15: scans re-tiled 1024->256/block. launch_bounds(256,8) NEUTRAL ->
//   gather latency-bound per-wave, not wave-starved.
// R16: quarter-wave 16-edge predicated gather: 115->100us (VALU 43%,
//   HBM 26%). Still latency-bound: duty cycle per wave ~9%.
// R17: edge-centric stream REGRESSED 100->225us (serial per-lane chain,
//   4 edges in flight/wave vs 16; occupancy 39%). REVERTED. Lesson:
//   edges-in-flight-per-wave is the objective function for this gather.
// R18: R16 structure + DUAL-NODE interleave: wave processes nodes (i,i+4)
//   concurrently -> 8 recs + 8 xb loads issued per round, 32 edges in
//   flight, 4 serial chains/wave instead of 8. VGPR ~95 -> (256,5)
//   (achieved occupancy was ~20 waves/CU anyway).
// ---------------------------------------------------------------------------

#define DFEAT 128
#define NREL 8
#define ALDA 264   // LDS agg row stride in ushorts (256 data + 8 pad)

typedef __attribute__((ext_vector_type(8))) short bf16x8;
typedef __attribute__((ext_vector_type(4))) float f32x4;
typedef __attribute__((ext_vector_type(2))) float f32x2;

__device__ __forceinline__ ushort f2bf(float f) {
    unsigned u = __float_as_uint(f);
    u += 0x7FFF + ((u >> 16) & 1);          // round-to-nearest-even
    return (ushort)(u >> 16);
}
__device__ __forceinline__ float bflo(unsigned u) { return __uint_as_float(u << 16); }
__device__ __forceinline__ float bfhi(unsigned u) { return __uint_as_float(u & 0xFFFF0000u); }
__device__ __forceinline__ unsigned pack2bf(float lo, float hi) {
    return (unsigned)f2bf(lo) | ((unsigned)f2bf(hi) << 16);
}

// Fused: count_rank (atomic-latency-bound) + convert_x + build_w2T (BW-bound).
// deg must be pre-zeroed. w2T[j][k]: k<256 -> bases[k>>7][k&127][j],
// else loopw[k-256][j].
__global__ void fused_pre(const int* __restrict__ dst, int* __restrict__ deg,
                          ushort* __restrict__ rank,
                          const float* __restrict__ x, ushort* __restrict__ xb,
                          const float* __restrict__ bases, const float* __restrict__ loopw,
                          ushort* __restrict__ w2T,
                          int RE, int E, int N, int n4) {
    const int stride = gridDim.x * blockDim.x;
    const int t0 = blockIdx.x * blockDim.x + threadIdx.x;
    for (int i = t0; i < RE; i += stride) {
        int r = i / E;
        int d = dst[i];
        rank[i] = (ushort)atomicAdd(&deg[r * N + d], 1);
    }
    for (int i = t0; i < n4; i += stride) {
        float4 v = ((const float4*)x)[i];
        ushort4 o;
        o.x = f2bf(v.x); o.y = f2bf(v.y); o.z = f2bf(v.z); o.w = f2bf(v.w);
        ((ushort4*)xb)[i] = o;
    }
    for (int i = t0; i < 128 * 384; i += stride) {
        int j = i / 384, k = i % 384;
        float v = (k < 256) ? bases[(k >> 7) * DFEAT * DFEAT + (k & 127) * DFEAT + j]
                            : loopw[(k - 256) * DFEAT + j];
        w2T[i] = f2bf(v);
    }
}

// Per 256-node chunk: cnt[d] = sum_r deg[r][d]; bsums[b] = chunk total.
__global__ void scan_block_sums(const int* __restrict__ deg, int* __restrict__ cnt,
                                int* __restrict__ bsums, int N) {
    __shared__ int sdata[256];
    int b = blockIdx.x, t = threadIdx.x;
    int idx = b * 256 + t;
    int sum = 0;
    if (idx < N) {
        #pragma unroll
        for (int r = 0; r < NREL; ++r) sum += deg[r * N + idx];
        cnt[idx] = sum;
    }
    sdata[t] = sum; __syncthreads();
    for (int s = 128; s > 0; s >>= 1) {
        if (t < s) sdata[t] += sdata[t + s];
        __syncthreads();
    }
    if (t == 0) bsums[b] = sdata[0];
}

// single-block exclusive scan of bsums[nb], nb <= 1024
__global__ void scan_mid(int* __restrict__ bsums, int nb) {
    __shared__ int s[256];
    int t = threadIdx.x;
    int base = t * 4;
    int v[4]; int sum = 0;
    #pragma unroll
    for (int i = 0; i < 4; ++i) {
        v[i] = sum;
        int c = (base + i < nb) ? bsums[base + i] : 0;
        sum += c;
    }
    s[t] = sum; __syncthreads();
    for (int off = 1; off < 256; off <<= 1) {
        int add = (t >= off) ? s[t - off] : 0;
        __syncthreads();
        s[t] += add;
        __syncthreads();
    }
    int excl = (t == 0) ? 0 : s[t - 1];
    #pragma unroll
    for (int i = 0; i < 4; ++i)
        if (base + i < nb) bsums[base + i] = excl + v[i];
}

// rowStart[d] + packed[r*N+d] = ((rowStart[d]+prefix_r)<<11)|deg_rd
__global__ void scan_write(const int* __restrict__ cnt, const int* __restrict__ bsums,
                           const int* __restrict__ deg,
                           int* __restrict__ rowStart, unsigned* __restrict__ packed,
                           int N) {
    __shared__ int tsum[256];
    int b = blockIdx.x, t = threadIdx.x;
    int idx = b * 256 + t;
    int c = (idx < N) ? cnt[idx] : 0;
    tsum[t] = c; __syncthreads();
    for (int off = 1; off < 256; off <<= 1) {
        int x = 0;
        if (t >= off) x = tsum[t - off];
        __syncthreads();
        if (t >= off) tsum[t] += x;
        __syncthreads();
    }
    int excl = (t == 0) ? 0 : tsum[t - 1];   // exclusive within block
    if (idx < N) {
        int rs = bsums[b] + excl;
        rowStart[idx] = rs;
        int pre = 0;
        #pragma unroll
        for (int r = 0; r < NREL; ++r) {
            int dv = deg[r * N + idx];
            packed[r * N + idx] = ((unsigned)(rs + pre) << 11) | (unsigned)dv;
            pre += dv;
        }
    }
}

// Atomic-free placement: pos = (packed>>11) + rank. ONE random read per edge.
__global__ void fill_kernel(const int* __restrict__ src, const int* __restrict__ dst,
                            const float* __restrict__ coeff,
                            const ushort* __restrict__ rank,
                            const unsigned* __restrict__ packed,
                            uint2* __restrict__ recs, int RE, int E, int N) {
    int idx = blockIdx.x * blockDim.x + threadIdx.x;
    if (idx >= RE) return;
    int r = idx / E;
    int d = dst[idx];
    unsigned p = packed[r * N + d];
    int pos = (int)(p >> 11) + (int)rank[idx];
    float inv = 1.0f / (float)(p & 2047u);
    __half2 hc = __floats2half2_rn(coeff[2 * r] * inv, coeff[2 * r + 1] * inv);
    uint2 rec;
    rec.x = (unsigned)src[idx];
    rec.y = *(unsigned*)&hc;
    recs[pos] = rec;
}

// ---------------------------------------------------------------------------
// FUSED gather + GEMM. Block = 32 dst nodes (row0..row0+31), LDS 16.9KB.
// Phase 1 (R18): wave w handles node pairs (i, i+4), i in {w, w+8, w+16,
//   w+24}. Per 16-edge round of EACH node: 4 recs loads + 4 uint4 row
//   loads, both nodes' loads issued back-to-back -> 32 edges in flight.
//   Predicated: invalid edges clamp index (safe, coeff 0). Reduce across
//   quarters via shfl_xor(16,32); q<2 lanes write 16B bf16 slices to LDS.
// Phase 2: out[32,128] = relu([aggLDS|xb][32,384] @ w2T^T + bias).
// ---------------------------------------------------------------------------
__global__ __launch_bounds__(256, 5) void gather_gemm(
    const uint2* __restrict__ recs, const int* __restrict__ rowStart,
    const int* __restrict__ cnt, const ushort* __restrict__ xb,
    const ushort* __restrict__ w2T, const float* __restrict__ bias,
    float* __restrict__ out, int N, int RE) {
    __shared__ __align__(16) ushort agg[32 * ALDA];   // 16.9 KB
    const int tid = threadIdx.x;
    const int wave = tid >> 6, lane = tid & 63;
    const int q = lane >> 4;        // quarter 0..3
    const int h = lane & 15;        // feature slot: features 8h..8h+7
    const int row0 = blockIdx.x * 32;

    // ---- phase 1: gather (dual-node) ----
    for (int i = wave; i < 32; i += 8) {
        const int dX = row0 + i;
        if (dX >= N) break;
        const int dY = dX + 4;
        const bool hasY = (dY < N);
        const int sX = rowStart[dX];
        const int lX = cnt[dX];
        const int sY = hasY ? rowStart[dY] : 0;
        const int lY = hasY ? cnt[dY] : 0;
        const int clX = (lX > 0) ? lX - 1 : 0;   // uniform clamps
        const int clY = (lY > 0) ? lY - 1 : 0;

        f32x2 XA0 = {0.f,0.f}, XA1 = {0.f,0.f}, XA2 = {0.f,0.f}, XA3 = {0.f,0.f};
        f32x2 XB0 = {0.f,0.f}, XB1 = {0.f,0.f}, XB2 = {0.f,0.f}, XB3 = {0.f,0.f};
        f32x2 YA0 = {0.f,0.f}, YA1 = {0.f,0.f}, YA2 = {0.f,0.f}, YA3 = {0.f,0.f};
        f32x2 YB0 = {0.f,0.f}, YB1 = {0.f,0.f}, YB2 = {0.f,0.f}, YB3 = {0.f,0.f};

        const int mx = (lX > lY) ? lX : lY;
        for (int i2 = 0; i2 < mx; i2 += 16) {
            uint2 rX[4], rY[4];
            #pragma unroll
            for (int j = 0; j < 4; ++j) {
                int e = i2 + 4 * j + q;
                int gX = sX + (e < lX ? e : clX);
                if (gX > RE - 1) gX = RE - 1;
                rX[j] = recs[gX];
                int gY = sY + (e < lY ? e : clY);
                if (gY > RE - 1) gY = RE - 1;
                rY[j] = recs[gY];
            }
            uint4 uX[4], uY[4];
            #pragma unroll
            for (int j = 0; j < 4; ++j) {
                uX[j] = *(const uint4*)(xb + (size_t)rX[j].x * DFEAT + h * 8);
                uY[j] = *(const uint4*)(xb + (size_t)rY[j].x * DFEAT + h * 8);
            }
            #pragma unroll
            for (int j = 0; j < 4; ++j) {
                int e = i2 + 4 * j + q;
                {
                    __half2 hc = *(__half2*)&rX[j].y;
                    bool v = e < lX;
                    float c0 = v ? __low2float(hc) : 0.f;
                    float c1 = v ? __high2float(hc) : 0.f;
                    f32x2 cc0 = {c0, c0}, cc1 = {c1, c1};
                    uint4 uu = uX[j];
                    f32x2 f01 = {bflo(uu.x), bfhi(uu.x)};
                    f32x2 f23 = {bflo(uu.y), bfhi(uu.y)};
                    f32x2 f45 = {bflo(uu.z), bfhi(uu.z)};
                    f32x2 f67 = {bflo(uu.w), bfhi(uu.w)};
                    XA0 += cc0 * f01; XA1 += cc0 * f23; XA2 += cc0 * f45; XA3 += cc0 * f67;
                    XB0 += cc1 * f01; XB1 += cc1 * f23; XB2 += cc1 * f45; XB3 += cc1 * f67;
                }
                {
                    __half2 hc = *(__half2*)&rY[j].y;
                    bool v = e < lY;
                    float c0 = v ? __low2float(hc) : 0.f;
                    float c1 = v ? __high2float(hc) : 0.f;
                    f32x2 cc0 = {c0, c0}, cc1 = {c1, c1};
                    uint4 uu = uY[j];
                    f32x2 f01 = {bflo(uu.x), bfhi(uu.x)};
                    f32x2 f23 = {bflo(uu.y), bfhi(uu.y)};
                    f32x2 f45 = {bflo(uu.z), bfhi(uu.z)};
                    f32x2 f67 = {bflo(uu.w), bfhi(uu.w)};
                    YA0 += cc0 * f01; YA1 += cc0 * f23; YA2 += cc0 * f45; YA3 += cc0 * f67;
                    YB0 += cc1 * f01; YB1 += cc1 * f23; YB2 += cc1 * f45; YB3 += cc1 * f67;
                }
            }
        }

        #define RED2(V) \
            V.x += __shfl_xor(V.x, 16); V.y += __shfl_xor(V.y, 16); \
            V.x += __shfl_xor(V.x, 32); V.y += __shfl_xor(V.y, 32);
        RED2(XA0) RED2(XA1) RED2(XA2) RED2(XA3)
        RED2(XB0) RED2(XB1) RED2(XB2) RED2(XB3)
        {
            f32x2 W0 = q ? XB0 : XA0, W1 = q ? XB1 : XA1;
            f32x2 W2 = q ? XB2 : XA2, W3 = q ? XB3 : XA3;
            uint4 w;
            w.x = pack2bf(W0.x, W0.y);
            w.y = pack2bf(W1.x, W1.y);
            w.z = pack2bf(W2.x, W2.y);
            w.w = pack2bf(W3.x, W3.y);
            if (q < 2)
                *(uint4*)(agg + i * ALDA + q * 128 + h * 8) = w;
        }
        if (hasY) {
            RED2(YA0) RED2(YA1) RED2(YA2) RED2(YA3)
            RED2(YB0) RED2(YB1) RED2(YB2) RED2(YB3)
            f32x2 W0 = q ? YB0 : YA0, W1 = q ? YB1 : YA1;
            f32x2 W2 = q ? YB2 : YA2, W3 = q ? YB3 : YA3;
            uint4 w;
            w.x = pack2bf(W0.x, W0.y);
            w.y = pack2bf(W1.x, W1.y);
            w.z = pack2bf(W2.x, W2.y);
            w.w = pack2bf(W3.x, W3.y);
            if (q < 2)
                *(uint4*)(agg + (i + 4) * ALDA + q * 128 + h * 8) = w;
        }
        #undef RED2
    }
    __syncthreads();

    // ---- phase 2: GEMM (M=32) ----
    const int quad = lane >> 4, l16 = lane & 15;
    int arow[2];
    #pragma unroll
    for (int m = 0; m < 2; ++m) {
        int r = row0 + m * 16 + l16;
        arow[m] = (r < N) ? r : 0;
    }

    f32x4 zero = {0.f, 0.f, 0.f, 0.f};
    f32x4 acc[2][2] = {{zero, zero}, {zero, zero}};

    #pragma unroll
    for (int kt = 0; kt < 3; ++kt) {
        bf16x8 bq[4][2];
        #pragma unroll
        for (int t = 0; t < 4; ++t)
            #pragma unroll
            for (int g = 0; g < 2; ++g)
                bq[t][g] = *(const bf16x8*)(w2T + (size_t)(wave * 32 + g * 16 + l16) * 384
                                            + kt * 128 + t * 32 + quad * 8);
        #pragma unroll
        for (int m = 0; m < 2; ++m) {
            #pragma unroll
            for (int t = 0; t < 4; ++t) {
                bf16x8 a;
                if (kt < 2)
                    a = *(const bf16x8*)(agg + (m * 16 + l16) * ALDA + kt * 128 + t * 32 + quad * 8);
                else
                    a = *(const bf16x8*)(xb + (size_t)arow[m] * DFEAT + t * 32 + quad * 8);
                acc[m][0] = __builtin_amdgcn_mfma_f32_16x16x32_bf16(a, bq[t][0], acc[m][0], 0, 0, 0);
                acc[m][1] = __builtin_amdgcn_mfma_f32_16x16x32_bf16(a, bq[t][1], acc[m][1], 0, 0, 0);
            }
        }
    }

    #pragma unroll
    for (int g = 0; g < 2; ++g) {
        int c = wave * 32 + g * 16 + l16;
        float bv = bias[c];
        #pragma unroll
        for (int m = 0; m < 2; ++m) {
            #pragma unroll
            for (int reg = 0; reg < 4; ++reg) {
                int grow = row0 + m * 16 + quad * 4 + reg;
                if (grow < N)
                    out[(size_t)grow * DFEAT + c] = fmaxf(acc[m][g][reg] + bv, 0.f);
            }
        }
    }
}

extern "C" void kernel_launch(void* const* d_in, const int* in_sizes, int n_in,
                              void* d_out, int out_size, void* d_ws, size_t ws_size,
                              hipStream_t stream) {
    const float* x     = (const float*)d_in[0];
    const int*   src   = (const int*)  d_in[1];
    const int*   dst   = (const int*)  d_in[2];
    const float* coeff = (const float*)d_in[3];
    const float* bases = (const float*)d_in[4];
    const float* loopw = (const float*)d_in[5];
    const float* bias  = (const float*)d_in[6];
    float* out = (float*)d_out;

    const int N  = in_sizes[0] / DFEAT;            // 100000
    const int RE = in_sizes[1];                    // R*E = 1200000
    const int B  = in_sizes[4] / (DFEAT * DFEAT);  // 2
    const int R  = in_sizes[3] / B;                // 8
    const int E  = RE / R;                         // 150000
    const int NB = (N + 255) / 256;                // scan blocks (391)

    // workspace layout
    char* ws = (char*)d_ws;
    size_t off = 0;
    auto alloc = [&](size_t bytes) { void* p = ws + off; off = (off + bytes + 255) & ~(size_t)255; return p; };
    int*      deg      = (int*)     alloc((size_t)R * N * sizeof(int));     // 3.2 MB
    ushort*   rank     = (ushort*)  alloc((size_t)RE * sizeof(ushort));     // 2.4 MB
    unsigned* packed   = (unsigned*)alloc((size_t)R * N * sizeof(unsigned));// 3.2 MB
    int*      cnt      = (int*)     alloc((size_t)N * sizeof(int));
    int*      rowStart = (int*)     alloc((size_t)N * sizeof(int));
    int*      bsums    = (int*)     alloc((size_t)NB * sizeof(int));
    ushort*   w2T      = (ushort*)  alloc((size_t)128 * 384 * sizeof(ushort));
    ushort*   xb       = (ushort*)  alloc((size_t)N * DFEAT * sizeof(ushort)); // 25.6 MB
    uint2*    recs     = (uint2*)   alloc((size_t)RE * sizeof(uint2));         // 9.6 MB

    hipMemsetAsync(deg, 0, (size_t)R * N * sizeof(int), stream);
    fused_pre<<<4096, 256, 0, stream>>>(dst, deg, rank, x, xb, bases, loopw, w2T,
                                        RE, E, N, N * 32);
    scan_block_sums<<<NB, 256, 0, stream>>>(deg, cnt, bsums, N);
    scan_mid<<<1, 256, 0, stream>>>(bsums, NB);
    scan_write<<<NB, 256, 0, stream>>>(cnt, bsums, deg, rowStart, packed, N);
    fill_kernel<<<(RE + 255) / 256, 256, 0, stream>>>(src, dst, coeff, rank, packed,
                                                      recs, RE, E, N);

    gather_gemm<<<(N + 31) / 32, 256, 0, stream>>>(recs, rowStart, cnt, xb, w2T,
                                                   bias, out, N, RE);
}

// Round 5
// 285.783 us; speedup vs baseline: 1.4298x; 1.0536x over previous
//
#include <hip/hip_runtime.h>
#include <hip/hip_fp16.h>

// ---------------------------------------------------------------------------
// RelGraphConv (basis-decomposed, right-norm, sum over relations) on MI355X.
//
//   h[d] = B0^T * A0[d] + B1^T * A1[d] + x[d]@Wl + bias,  ReLU
//   A_b[d] = sum_{edges e->d} (coeff[r_e][b]/deg[r_e][d]) * x[src_e]
// R16: quarter-wave 16-edge predicated gather: 100us (VALU 43%, HBM 26%).
// R17: edge-centric stream REGRESSED (serial chain). REVERTED.
// R18: dual-node interleave REGRESSED (VGPR 48, occ 45%, dup-load waste
//   on max(lX,lY) loop). REVERTED. Lesson: the limit is the FRACTION of
//   wave-time with gathers outstanding (miss-duty-cycle), not burst size.
// R19: stage block's recs (contiguous CSR range, ~384 edges) + 33 rowStarts
//   into LDS once. Quarter-wave owns a node (16 lanes x 8 feats = full row);
//   8-edge rounds with rec addresses from LDS (~120cy, not ~900cy global);
//   4 independent node-chains/wave, 32 edge-rows in flight; NO shuffle
//   reduce, NO per-node global rowStart/cnt chain, no tail imbalance
//   within quarter. Block-uniform global-recs fallback if cntE > 1024
//   (can't happen for Poisson(384), kept for correctness).
// ---------------------------------------------------------------------------

#define DFEAT 128
#define NREL 8
#define ALDA 264   // LDS agg row stride in ushorts (256 data + 8 pad)
#define ECAP 1024  // staged-recs capacity (block edge count ~Poisson(384))

typedef __attribute__((ext_vector_type(8))) short bf16x8;
typedef __attribute__((ext_vector_type(4))) float f32x4;
typedef __attribute__((ext_vector_type(2))) float f32x2;

__device__ __forceinline__ ushort f2bf(float f) {
    unsigned u = __float_as_uint(f);
    u += 0x7FFF + ((u >> 16) & 1);          // round-to-nearest-even
    return (ushort)(u >> 16);
}
__device__ __forceinline__ float bflo(unsigned u) { return __uint_as_float(u << 16); }
__device__ __forceinline__ float bfhi(unsigned u) { return __uint_as_float(u & 0xFFFF0000u); }
__device__ __forceinline__ unsigned pack2bf(float lo, float hi) {
    return (unsigned)f2bf(lo) | ((unsigned)f2bf(hi) << 16);
}

// Fused: count_rank (atomic-latency-bound) + convert_x + build_w2T (BW-bound).
// deg must be pre-zeroed. w2T[j][k]: k<256 -> bases[k>>7][k&127][j],
// else loopw[k-256][j].
__global__ void fused_pre(const int* __restrict__ dst, int* __restrict__ deg,
                          ushort* __restrict__ rank,
                          const float* __restrict__ x, ushort* __restrict__ xb,
                          const float* __restrict__ bases, const float* __restrict__ loopw,
                          ushort* __restrict__ w2T,
                          int RE, int E, int N, int n4) {
    const int stride = gridDim.x * blockDim.x;
    const int t0 = blockIdx.x * blockDim.x + threadIdx.x;
    for (int i = t0; i < RE; i += stride) {
        int r = i / E;
        int d = dst[i];
        rank[i] = (ushort)atomicAdd(&deg[r * N + d], 1);
    }
    for (int i = t0; i < n4; i += stride) {
        float4 v = ((const float4*)x)[i];
        ushort4 o;
        o.x = f2bf(v.x); o.y = f2bf(v.y); o.z = f2bf(v.z); o.w = f2bf(v.w);
        ((ushort4*)xb)[i] = o;
    }
    for (int i = t0; i < 128 * 384; i += stride) {
        int j = i / 384, k = i % 384;
        float v = (k < 256) ? bases[(k >> 7) * DFEAT * DFEAT + (k & 127) * DFEAT + j]
                            : loopw[(k - 256) * DFEAT + j];
        w2T[i] = f2bf(v);
    }
}

// Per 256-node chunk: cnt[d] = sum_r deg[r][d]; bsums[b] = chunk total.
__global__ void scan_block_sums(const int* __restrict__ deg, int* __restrict__ cnt,
                                int* __restrict__ bsums, int N) {
    __shared__ int sdata[256];
    int b = blockIdx.x, t = threadIdx.x;
    int idx = b * 256 + t;
    int sum = 0;
    if (idx < N) {
        #pragma unroll
        for (int r = 0; r < NREL; ++r) sum += deg[r * N + idx];
        cnt[idx] = sum;
    }
    sdata[t] = sum; __syncthreads();
    for (int s = 128; s > 0; s >>= 1) {
        if (t < s) sdata[t] += sdata[t + s];
        __syncthreads();
    }
    if (t == 0) bsums[b] = sdata[0];
}

// single-block exclusive scan of bsums[nb], nb <= 1024
__global__ void scan_mid(int* __restrict__ bsums, int nb) {
    __shared__ int s[256];
    int t = threadIdx.x;
    int base = t * 4;
    int v[4]; int sum = 0;
    #pragma unroll
    for (int i = 0; i < 4; ++i) {
        v[i] = sum;
        int c = (base + i < nb) ? bsums[base + i] : 0;
        sum += c;
    }
    s[t] = sum; __syncthreads();
    for (int off = 1; off < 256; off <<= 1) {
        int add = (t >= off) ? s[t - off] : 0;
        __syncthreads();
        s[t] += add;
        __syncthreads();
    }
    int excl = (t == 0) ? 0 : s[t - 1];
    #pragma unroll
    for (int i = 0; i < 4; ++i)
        if (base + i < nb) bsums[base + i] = excl + v[i];
}

// rowStart[d] + packed[r*N+d] = ((rowStart[d]+prefix_r)<<11)|deg_rd
__global__ void scan_write(const int* __restrict__ cnt, const int* __restrict__ bsums,
                           const int* __restrict__ deg,
                           int* __restrict__ rowStart, unsigned* __restrict__ packed,
                           int N) {
    __shared__ int tsum[256];
    int b = blockIdx.x, t = threadIdx.x;
    int idx = b * 256 + t;
    int c = (idx < N) ? cnt[idx] : 0;
    tsum[t] = c; __syncthreads();
    for (int off = 1; off < 256; off <<= 1) {
        int x = 0;
        if (t >= off) x = tsum[t - off];
        __syncthreads();
        if (t >= off) tsum[t] += x;
        __syncthreads();
    }
    int excl = (t == 0) ? 0 : tsum[t - 1];   // exclusive within block
    if (idx < N) {
        int rs = bsums[b] + excl;
        rowStart[idx] = rs;
        int pre = 0;
        #pragma unroll
        for (int r = 0; r < NREL; ++r) {
            int dv = deg[r * N + idx];
            packed[r * N + idx] = ((unsigned)(rs + pre) << 11) | (unsigned)dv;
            pre += dv;
        }
    }
}

// Atomic-free placement: pos = (packed>>11) + rank. ONE random read per edge.
__global__ void fill_kernel(const int* __restrict__ src, const int* __restrict__ dst,
                            const float* __restrict__ coeff,
                            const ushort* __restrict__ rank,
                            const unsigned* __restrict__ packed,
                            uint2* __restrict__ recs, int RE, int E, int N) {
    int idx = blockIdx.x * blockDim.x + threadIdx.x;
    if (idx >= RE) return;
    int r = idx / E;
    int d = dst[idx];
    unsigned p = packed[r * N + d];
    int pos = (int)(p >> 11) + (int)rank[idx];
    float inv = 1.0f / (float)(p & 2047u);
    __half2 hc = __floats2half2_rn(coeff[2 * r] * inv, coeff[2 * r + 1] * inv);
    uint2 rec;
    rec.x = (unsigned)src[idx];
    rec.y = *(unsigned*)&hc;
    recs[pos] = rec;
}

// ---------------------------------------------------------------------------
// FUSED gather + GEMM. Block = 32 dst nodes, LDS 16.9KB agg + 8KB recs.
// Phase 0: stage rowStart[row0..row0+32] and recs[e0..e1) into LDS.
// Phase 1: quarter-wave qw owns nodes {qw, qw+16}; 16 lanes cover 128
//   feats; 8-edge rounds, rec from LDS (broadcast read), xb uint4 gather.
//   Accumulate f32; write c0 slice to agg[i][h*8], c1 to agg[i][128+h*8].
// Phase 2: out[32,128] = relu([aggLDS|xb][32,384] @ w2T^T + bias).
// ---------------------------------------------------------------------------
__global__ __launch_bounds__(256, 5) void gather_gemm(
    const uint2* __restrict__ recs, const int* __restrict__ rowStart,
    const ushort* __restrict__ xb,
    const ushort* __restrict__ w2T, const float* __restrict__ bias,
    float* __restrict__ out, int N, int RE) {
    __shared__ __align__(16) ushort agg[32 * ALDA];   // 16.9 KB
    __shared__ __align__(16) uint2 recsL[ECAP];       // 8 KB
    __shared__ int rsl[33];
    const int tid = threadIdx.x;
    const int wave = tid >> 6, lane = tid & 63;
    const int row0 = blockIdx.x * 32;

    // ---- phase 0: stage rowStarts + recs ----
    if (tid < 33) {
        int d = row0 + tid;
        rsl[tid] = (d < N) ? rowStart[d] : RE;
    }
    __syncthreads();
    const int e0 = rsl[0];
    const int cntE = rsl[32] - e0;
    const bool fits = (cntE <= ECAP);
    {
        const int lim = fits ? cntE : 0;
        for (int k = tid; k < lim; k += 256)
            recsL[k] = recs[e0 + k];
    }
    __syncthreads();

    // ---- phase 1: gather (quarter-wave per node) ----
    {
        const int qw = tid >> 4;        // quarter-wave id 0..15
        const int h  = tid & 15;        // feature slot: feats 8h..8h+7

        auto gatherNode = [&](int i, auto getRec) {
            const int s   = rsl[i] - e0;
            const int len = rsl[i + 1] - rsl[i];
            f32x2 A0 = {0.f,0.f}, A1 = {0.f,0.f}, A2 = {0.f,0.f}, A3 = {0.f,0.f};
            f32x2 B0 = {0.f,0.f}, B1 = {0.f,0.f}, B2 = {0.f,0.f}, B3 = {0.f,0.f};
            if (len > 0) {
                const int last = s + len - 1;
                for (int k = 0; k < len; k += 8) {
                    uint2 rc[8];
                    #pragma unroll
                    for (int j = 0; j < 8; ++j) {
                        int li = s + k + j;
                        rc[j] = getRec(li <= last ? li : last);
                    }
                    uint4 u[8];
                    #pragma unroll
                    for (int j = 0; j < 8; ++j)
                        u[j] = *(const uint4*)(xb + (size_t)rc[j].x * DFEAT + h * 8);
                    #pragma unroll
                    for (int j = 0; j < 8; ++j) {
                        bool v = (k + j) < len;
                        __half2 hc = *(__half2*)&rc[j].y;
                        float c0 = v ? __low2float(hc) : 0.f;
                        float c1 = v ? __high2float(hc) : 0.f;
                        f32x2 cc0 = {c0, c0}, cc1 = {c1, c1};
                        uint4 uu = u[j];
                        f32x2 f01 = {bflo(uu.x), bfhi(uu.x)};
                        f32x2 f23 = {bflo(uu.y), bfhi(uu.y)};
                        f32x2 f45 = {bflo(uu.z), bfhi(uu.z)};
                        f32x2 f67 = {bflo(uu.w), bfhi(uu.w)};
                        A0 += cc0 * f01; A1 += cc0 * f23; A2 += cc0 * f45; A3 += cc0 * f67;
                        B0 += cc1 * f01; B1 += cc1 * f23; B2 += cc1 * f45; B3 += cc1 * f67;
                    }
                }
            }
            uint4 w0, w1;
            w0.x = pack2bf(A0.x, A0.y); w0.y = pack2bf(A1.x, A1.y);
            w0.z = pack2bf(A2.x, A2.y); w0.w = pack2bf(A3.x, A3.y);
            w1.x = pack2bf(B0.x, B0.y); w1.y = pack2bf(B1.x, B1.y);
            w1.z = pack2bf(B2.x, B2.y); w1.w = pack2bf(B3.x, B3.y);
            *(uint4*)(agg + i * ALDA + h * 8)       = w0;   // c0 feats
            *(uint4*)(agg + i * ALDA + 128 + h * 8) = w1;   // c1 feats
        };

        if (fits) {
            #pragma unroll
            for (int p = 0; p < 2; ++p)
                gatherNode(qw + p * 16, [&](int li) { return recsL[li]; });
        } else {
            #pragma unroll
            for (int p = 0; p < 2; ++p)
                gatherNode(qw + p * 16, [&](int li) { return recs[e0 + li]; });
        }
    }
    __syncthreads();

    // ---- phase 2: GEMM (M=32) ----
    const int quad = lane >> 4, l16 = lane & 15;
    int arow[2];
    #pragma unroll
    for (int m = 0; m < 2; ++m) {
        int r = row0 + m * 16 + l16;
        arow[m] = (r < N) ? r : 0;
    }

    f32x4 zero = {0.f, 0.f, 0.f, 0.f};
    f32x4 acc[2][2] = {{zero, zero}, {zero, zero}};

    #pragma unroll
    for (int kt = 0; kt < 3; ++kt) {
        bf16x8 bq[4][2];
        #pragma unroll
        for (int t = 0; t < 4; ++t)
            #pragma unroll
            for (int g = 0; g < 2; ++g)
                bq[t][g] = *(const bf16x8*)(w2T + (size_t)(wave * 32 + g * 16 + l16) * 384
                                            + kt * 128 + t * 32 + quad * 8);
        #pragma unroll
        for (int m = 0; m < 2; ++m) {
            #pragma unroll
            for (int t = 0; t < 4; ++t) {
                bf16x8 a;
                if (kt < 2)
                    a = *(const bf16x8*)(agg + (m * 16 + l16) * ALDA + kt * 128 + t * 32 + quad * 8);
                else
                    a = *(const bf16x8*)(xb + (size_t)arow[m] * DFEAT + t * 32 + quad * 8);
                acc[m][0] = __builtin_amdgcn_mfma_f32_16x16x32_bf16(a, bq[t][0], acc[m][0], 0, 0, 0);
                acc[m][1] = __builtin_amdgcn_mfma_f32_16x16x32_bf16(a, bq[t][1], acc[m][1], 0, 0, 0);
            }
        }
    }

    #pragma unroll
    for (int g = 0; g < 2; ++g) {
        int c = wave * 32 + g * 16 + l16;
        float bv = bias[c];
        #pragma unroll
        for (int m = 0; m < 2; ++m) {
            #pragma unroll
            for (int reg = 0; reg < 4; ++reg) {
                int grow = row0 + m * 16 + quad * 4 + reg;
                if (grow < N)
                    out[(size_t)grow * DFEAT + c] = fmaxf(acc[m][g][reg] + bv, 0.f);
            }
        }
    }
}

extern "C" void kernel_launch(void* const* d_in, const int* in_sizes, int n_in,
                              void* d_out, int out_size, void* d_ws, size_t ws_size,
                              hipStream_t stream) {
    const float* x     = (const float*)d_in[0];
    const int*   src   = (const int*)  d_in[1];
    const int*   dst   = (const int*)  d_in[2];
    const float* coeff = (const float*)d_in[3];
    const float* bases = (const float*)d_in[4];
    const float* loopw = (const float*)d_in[5];
    const float* bias  = (const float*)d_in[6];
    float* out = (float*)d_out;

    const int N  = in_sizes[0] / DFEAT;            // 100000
    const int RE = in_sizes[1];                    // R*E = 1200000
    const int B  = in_sizes[4] / (DFEAT * DFEAT);  // 2
    const int R  = in_sizes[3] / B;                // 8
    const int E  = RE / R;                         // 150000
    const int NB = (N + 255) / 256;                // scan blocks (391)

    // workspace layout
    char* ws = (char*)d_ws;
    size_t off = 0;
    auto alloc = [&](size_t bytes) { void* p = ws + off; off = (off + bytes + 255) & ~(size_t)255; return p; };
    int*      deg      = (int*)     alloc((size_t)R * N * sizeof(int));     // 3.2 MB
    ushort*   rank     = (ushort*)  alloc((size_t)RE * sizeof(ushort));     // 2.4 MB
    unsigned* packed   = (unsigned*)alloc((size_t)R * N * sizeof(unsigned));// 3.2 MB
    int*      cnt      = (int*)     alloc((size_t)N * sizeof(int));
    int*      rowStart = (int*)     alloc((size_t)N * sizeof(int));
    int*      bsums    = (int*)     alloc((size_t)NB * sizeof(int));
    ushort*   w2T      = (ushort*)  alloc((size_t)128 * 384 * sizeof(ushort));
    ushort*   xb       = (ushort*)  alloc((size_t)N * DFEAT * sizeof(ushort)); // 25.6 MB
    uint2*    recs     = (uint2*)   alloc((size_t)RE * sizeof(uint2));         // 9.6 MB

    hipMemsetAsync(deg, 0, (size_t)R * N * sizeof(int), stream);
    fused_pre<<<4096, 256, 0, stream>>>(dst, deg, rank, x, xb, bases, loopw, w2T,
                                        RE, E, N, N * 32);
    scan_block_sums<<<NB, 256, 0, stream>>>(deg, cnt, bsums, N);
    scan_mid<<<1, 256, 0, stream>>>(bsums, NB);
    scan_write<<<NB, 256, 0, stream>>>(cnt, bsums, deg, rowStart, packed, N);
    fill_kernel<<<(RE + 255) / 256, 256, 0, stream>>>(src, dst, coeff, rank, packed,
                                                      recs, RE, E, N);

    gather_gemm<<<(N + 31) / 32, 256, 0, stream>>>(recs, rowStart, xb, w2T,
                                                   bias, out, N, RE);
}